// Round 3
// baseline (175.257 us; speedup 1.0000x reference)
//
#include <hip/hip_runtime.h>
#include <math.h>

// Exact IEEE semantics in the visibility path: no fma contraction anywhere.
#pragma clang fp contract(off)

#define IMG_H 128
#define IMG_W 128
#define HW (IMG_H * IMG_W)
#define NB 2
#define NV 1300
#define NF 2500
#define EPSF 1e-8f
#define NCHUNK 16
#define CHUNK ((NF + NCHUNK - 1) / NCHUNK) // 157

// ws layout (bytes):
//   vert   f4 [NB*NV]            @ 0       (41600 B)  {ndcx, ndcy, z, 0}
//   vn     f32[NB*NV*3]          @ 41600   (31200 B)
//   face   f4 [NB*NF*4]          @ 72800   (320000 B)
//   dbuf16 u64[NCHUNK][NB][HW]   @ 392800  (4 MB)     per-chunk depth|idx
#define OFF_VN 41600
#define OFF_FACE 72800
#define OFF_DBUF 392800

#define DINIT 0x7F800000FFFFFFFFull // depth=+inf, fidx=~0

__global__ __launch_bounds__(256) void k_init(const float* __restrict__ verts,
                                              float4* __restrict__ vert,
                                              float* __restrict__ vn) {
    int i = blockIdx.x * 256 + threadIdx.x;
    if (i < NB * NV * 3) vn[i] = 0.0f;
    if (i < NB * NV) {
        float vx = verts[i * 3 + 0];
        float vy = verts[i * 3 + 1];
        float vz = verts[i * 3 + 2];
        float viewx = -vx;
        float viewy = vy;
        float z = 2.0f - vz;
        float ndcx = (12.0f * viewx) / z;
        float ndcy = (12.0f * viewy) / z;
        vert[i] = make_float4(ndcx, ndcy, z, 0.0f);
    }
}

__global__ __launch_bounds__(256) void k_face(const float* __restrict__ verts,
                                              const int* __restrict__ faces,
                                              const float4* __restrict__ vert,
                                              float* __restrict__ vn,
                                              float4* __restrict__ face) {
    int i = blockIdx.x * 256 + threadIdx.x;
    if (i >= NB * NF) return;
    int b = i / NF;
    int f = i - b * NF;
    int i0 = faces[f * 3 + 0];
    int i1 = faces[f * 3 + 1];
    int i2 = faces[f * 3 + 2];
    float4 p0 = vert[b * NV + i0];
    float4 p1 = vert[b * NV + i1];
    float4 p2 = vert[b * NV + i2];
    float t1 = (p1.x - p0.x) * (p2.y - p0.y);
    float t2 = (p1.y - p0.y) * (p2.x - p0.x);
    float area = t1 - t2;
    float aabs = fabsf(area);
    float area_safe = (aabs < EPSF) ? EPSF : area;
    bool valid = aabs > EPSF;
    float minx, maxx, miny, maxy;
    if (valid) {
        minx = fminf(p0.x, fminf(p1.x, p2.x)) - 1e-3f;
        maxx = fmaxf(p0.x, fmaxf(p1.x, p2.x)) + 1e-3f;
        miny = fminf(p0.y, fminf(p1.y, p2.y)) - 1e-3f;
        maxy = fmaxf(p0.y, fmaxf(p1.y, p2.y)) + 1e-3f;
    } else {
        minx = 1e30f; maxx = -1e30f; miny = 1e30f; maxy = -1e30f;
    }
    int o = (b * NF + f) * 4;
    face[o + 0] = make_float4(p2.x - p1.x, p2.y - p1.y, p1.x, p1.y);
    face[o + 1] = make_float4(p0.x - p2.x, p0.y - p2.y, p2.x, p2.y);
    face[o + 2] = make_float4(area_safe, p0.z, p1.z, p2.z);
    face[o + 3] = make_float4(minx, maxx, miny, maxy);

    const float* wv = verts + (size_t)b * NV * 3;
    float ax = wv[i1 * 3 + 0] - wv[i0 * 3 + 0];
    float ay = wv[i1 * 3 + 1] - wv[i0 * 3 + 1];
    float az = wv[i1 * 3 + 2] - wv[i0 * 3 + 2];
    float bx = wv[i2 * 3 + 0] - wv[i0 * 3 + 0];
    float by = wv[i2 * 3 + 1] - wv[i0 * 3 + 1];
    float bz = wv[i2 * 3 + 2] - wv[i0 * 3 + 2];
    float fnx = ay * bz - az * by;
    float fny = az * bx - ax * bz;
    float fnz = ax * by - ay * bx;
    float* vnb = vn + (size_t)b * NV * 3;
    atomicAdd(&vnb[i0 * 3 + 0], fnx);
    atomicAdd(&vnb[i0 * 3 + 1], fny);
    atomicAdd(&vnb[i0 * 3 + 2], fnz);
    atomicAdd(&vnb[i1 * 3 + 0], fnx);
    atomicAdd(&vnb[i1 * 3 + 1], fny);
    atomicAdd(&vnb[i1 * 3 + 2], fnz);
    atomicAdd(&vnb[i2 * 3 + 0], fnx);
    atomicAdd(&vnb[i2 * 3 + 1], fny);
    atomicAdd(&vnb[i2 * 3 + 2], fnz);
}

// Grid: 64 tiles (16x16 px) x NB x NCHUNK. Wave = 8x8 quadrant. Face chunk
// staged in LDS. NO atomics: each lane writes its per-chunk best with a plain
// store (8 u64-rows of 64 B per wave -> fully line-coalesced); k_shade merges.
__global__ __launch_bounds__(256) void k_raster(const float4* __restrict__ face,
                                                unsigned long long* __restrict__ dbuf16) {
    __shared__ float4 sface[(CHUNK + 1) * 4];
    int bx = blockIdx.x;
    int tile = bx & 63;
    int b = (bx >> 6) & 1;
    int chunk = bx >> 7;
    int f0 = chunk * CHUNK;
    int nf = NF - f0; if (nf > CHUNK) nf = CHUNK;

    const float4* fb = face + (size_t)b * NF * 4 + (size_t)f0 * 4;
    for (int t = threadIdx.x; t < nf * 4; t += 256) sface[t] = fb[t];
    if (threadIdx.x < 4) sface[nf * 4 + threadIdx.x] = make_float4(5.0f, -5.0f, 5.0f, -5.0f);
    __syncthreads();

    int w = threadIdx.x >> 6;
    int l = threadIdx.x & 63;
    int r = ((tile >> 3) * 16) + ((w >> 1) * 8) + (l >> 3);
    int c = ((tile & 7) * 16) + ((w & 1) * 8) + (l & 7);
    int p = r * IMG_W + c;
    float px = 1.0f - (2.0f * (float)c + 1.0f) / 128.0f;
    float py = 1.0f - (2.0f * (float)r + 1.0f) / 128.0f;

    unsigned long long best = DINIT;
    float4 bbn = sface[3]; // prefetch j=0's bbox
    for (int j = 0; j < nf; ++j) {
        float4 bb = bbn;
        bbn = sface[(j + 1) * 4 + 3]; // padded slot makes j+1 always valid
        if (px >= bb.x && px <= bb.y && py >= bb.z && py <= bb.w) {
            float4 E0 = sface[j * 4 + 0];
            float4 E1 = sface[j * 4 + 1];
            float4 FD = sface[j * 4 + 2];
            // exact ref order: e = (bx-ax)*(py-ay) - (by-ay)*(px-ax)
            float u1 = E0.x * (py - E0.w);
            float u2 = E0.y * (px - E0.z);
            float e0 = u1 - u2;
            float u3 = E1.x * (py - E1.w);
            float u4 = E1.y * (px - E1.z);
            float e1 = u3 - u4;
            float as = FD.x;
            bool ok = (as > 0.0f) ? (e0 >= 0.0f && e1 >= 0.0f)
                                  : (e0 <= 0.0f && e1 <= 0.0f);
            if (ok) {
                float b0 = e0 / as; // true IEEE division, as in ref
                float b1 = e1 / as;
                float b2 = (1.0f - b0) - b1;
                if (b2 >= 0.0f) {
                    float S = ((b0 / FD.y) + (b1 / FD.z)) + (b2 / FD.w);
                    if (S > EPSF) {
                        float depth = 1.0f / fmaxf(S, EPSF);
                        unsigned long long pk =
                            ((unsigned long long)__float_as_uint(depth) << 32) |
                            (unsigned)(f0 + j);
                        if (pk < best) best = pk;
                    }
                }
            }
        }
    }
    dbuf16[((size_t)chunk * NB + b) * HW + p] = best;
}

__global__ __launch_bounds__(256) void k_shade(const float* __restrict__ verts,
                                               const int* __restrict__ faces,
                                               const float4* __restrict__ vert,
                                               const float* __restrict__ vn,
                                               const unsigned long long* __restrict__ dbuf16,
                                               float* __restrict__ out) {
    int i = blockIdx.x * 256 + threadIdx.x; // 0..NB*HW-1
    int b = i >> 14;
    int p = i & (HW - 1);
    // merge the 16 per-chunk bests (u64 min == atomicMin result, incl. ties)
    unsigned long long pk = DINIT;
    for (int k = 0; k < NCHUNK; ++k) {
        unsigned long long v = dbuf16[((size_t)k * NB + b) * HW + p];
        if (v < pk) pk = v;
    }
    unsigned dbits = (unsigned)(pk >> 32);
    bool hit = dbits < 0x7F800000u;
    float cr = 255.0f, cg = 255.0f, cb = 255.0f, alpha = 0.0f;
    if (hit) {
        alpha = 1.0f;
        int f = (int)(unsigned)(pk & 0xFFFFFFFFull);
        int row = p >> 7;
        int col = p & 127;
        float px = 1.0f - (2.0f * (float)col + 1.0f) / 128.0f;
        float py = 1.0f - (2.0f * (float)row + 1.0f) / 128.0f;
        int i0 = faces[f * 3 + 0];
        int i1 = faces[f * 3 + 1];
        int i2 = faces[f * 3 + 2];
        float4 a0 = vert[b * NV + i0];
        float4 a1 = vert[b * NV + i1];
        float4 a2 = vert[b * NV + i2];
        float t1 = (a1.x - a0.x) * (a2.y - a0.y);
        float t2 = (a1.y - a0.y) * (a2.x - a0.x);
        float ar = t1 - t2;
        ar = (fabsf(ar) < EPSF) ? EPSF : ar;
        float u1 = (a2.x - a1.x) * (py - a1.y);
        float u2 = (a2.y - a1.y) * (px - a1.x);
        float bb0 = (u1 - u2) / ar;
        float u3 = (a0.x - a2.x) * (py - a2.y);
        float u4 = (a0.y - a2.y) * (px - a2.x);
        float bb1 = (u3 - u4) / ar;
        float bb2 = (1.0f - bb0) - bb1;
        float w0 = bb0 / a0.z;
        float w1 = bb1 / a1.z;
        float w2 = bb2 / a2.z;
        float denom = ((w0 + w1) + w2) + EPSF;
        float pc0 = w0 / denom;
        float pc1 = w1 / denom;
        float pc2 = w2 / denom;

        const float* wv = verts + (size_t)b * NV * 3;
        float v0x = wv[i0 * 3 + 0], v0y = wv[i0 * 3 + 1], v0z = wv[i0 * 3 + 2];
        float v1x = wv[i1 * 3 + 0], v1y = wv[i1 * 3 + 1], v1z = wv[i1 * 3 + 2];
        float v2x = wv[i2 * 3 + 0], v2y = wv[i2 * 3 + 1], v2z = wv[i2 * 3 + 2];
        float posx = (pc0 * v0x + pc1 * v1x) + pc2 * v2x;
        float posy = (pc0 * v0y + pc1 * v1y) + pc2 * v2y;
        float posz = (pc0 * v0z + pc1 * v1z) + pc2 * v2z;

        const float* vnb = vn + (size_t)b * NV * 3;
        float n0x = vnb[i0 * 3 + 0], n0y = vnb[i0 * 3 + 1], n0z = vnb[i0 * 3 + 2];
        float n1x = vnb[i1 * 3 + 0], n1y = vnb[i1 * 3 + 1], n1z = vnb[i1 * 3 + 2];
        float n2x = vnb[i2 * 3 + 0], n2y = vnb[i2 * 3 + 1], n2z = vnb[i2 * 3 + 2];
        float in0 = 1.0f / (sqrtf(n0x * n0x + n0y * n0y + n0z * n0z) + EPSF);
        float in1 = 1.0f / (sqrtf(n1x * n1x + n1y * n1y + n1z * n1z) + EPSF);
        float in2 = 1.0f / (sqrtf(n2x * n2x + n2y * n2y + n2z * n2z) + EPSF);
        n0x *= in0; n0y *= in0; n0z *= in0;
        n1x *= in1; n1y *= in1; n1z *= in1;
        n2x *= in2; n2y *= in2; n2z *= in2;
        float nx = (pc0 * n0x + pc1 * n1x) + pc2 * n2x;
        float ny = (pc0 * n0y + pc1 * n1y) + pc2 * n2y;
        float nz = (pc0 * n0z + pc1 * n1z) + pc2 * n2z;
        float inn = 1.0f / (sqrtf(nx * nx + ny * ny + nz * nz) + EPSF);
        nx *= inn; ny *= inn; nz *= inn;

        float lx = 0.0f - posx, ly = 1.0f - posy, lz = 3.0f - posz;
        float iln = 1.0f / (sqrtf(lx * lx + ly * ly + lz * lz) + EPSF);
        lx *= iln; ly *= iln; lz *= iln;
        float vx = 0.0f - posx, vy = 0.0f - posy, vz = 2.0f - posz;
        float ivn = 1.0f / (sqrtf(vx * vx + vy * vy + vz * vz) + EPSF);
        vx *= ivn; vy *= ivn; vz *= ivn;

        float ndl = nx * lx + ny * ly + nz * lz;
        float ndlr = fmaxf(ndl, 0.0f);
        float rx = 2.0f * ndl * nx - lx;
        float ry = 2.0f * ndl * ny - ly;
        float rz = 2.0f * ndl * nz - lz;
        float sc = fmaxf(rx * vx + ry * vy + rz * vz, 0.0f);
        float spec = 0.2f * 0.6f * powf(sc, 10.0f);
        float shade = 0.5f * 1.0f + 0.3f * 1.0f * ndlr;
        cr = ((142.0f / 255.0f) * shade + spec) * 255.0f;
        cg = ((179.0f / 255.0f) * shade + spec) * 255.0f;
        cb = ((247.0f / 255.0f) * shade + spec) * 255.0f;
    }
    float* img = out + (size_t)b * 3 * HW;
    img[0 * HW + p] = cr;
    img[1 * HW + p] = cg;
    img[2 * HW + p] = cb;
    out[(size_t)NB * 3 * HW + (size_t)b * HW + p] = alpha;
}

extern "C" void kernel_launch(void* const* d_in, const int* in_sizes, int n_in,
                              void* d_out, int out_size, void* d_ws, size_t ws_size,
                              hipStream_t stream) {
    const float* verts = (const float*)d_in[0]; // [NB, NV, 3]
    const int* faces = (const int*)d_in[1];     // [NF, 3]
    char* ws = (char*)d_ws;
    float4* vert = (float4*)(ws + 0);
    float* vn = (float*)(ws + OFF_VN);
    float4* face = (float4*)(ws + OFF_FACE);
    unsigned long long* dbuf16 = (unsigned long long*)(ws + OFF_DBUF);
    float* out = (float*)d_out;

    k_init<<<(NB * NV * 3 + 255) / 256, 256, 0, stream>>>(verts, vert, vn);
    k_face<<<(NB * NF + 255) / 256, 256, 0, stream>>>(verts, faces, vert, vn, face);
    k_raster<<<64 * NB * NCHUNK, 256, 0, stream>>>(face, dbuf16);
    k_shade<<<(NB * HW) / 256, 256, 0, stream>>>(verts, faces, vert, vn, dbuf16, out);
}

// Round 4
// 128.141 us; speedup vs baseline: 1.3677x; 1.3677x over previous
//
#include <hip/hip_runtime.h>
#include <math.h>

// Exact IEEE semantics in the visibility path: no fma contraction anywhere.
#pragma clang fp contract(off)

#define IMG_H 128
#define IMG_W 128
#define HW (IMG_H * IMG_W)
#define NB 2
#define NV 1300
#define NF 2500
#define EPSF 1e-8f
#define NCHUNK 16
#define CHUNK ((NF + NCHUNK - 1) / NCHUNK) // 157

// ws layout (bytes):
//   vert   f4 [NB*NV]            @ 0       (41600 B)  {ndcx, ndcy, z, 0}
//   vn     f32[NB*NV*3]          @ 41600   (31200 B)
//   face   f4 [NB*NF*4]          @ 72800   (320000 B)
//   dbuf16 u64[NCHUNK][NB][HW]   @ 392800  (4 MB)     per-chunk depth|idx
#define OFF_VN 41600
#define OFF_FACE 72800
#define OFF_DBUF 392800

#define DINIT 0x7F800000FFFFFFFFull // depth=+inf, fidx=~0

__global__ __launch_bounds__(256) void k_init(const float* __restrict__ verts,
                                              float4* __restrict__ vert,
                                              float* __restrict__ vn) {
    int i = blockIdx.x * 256 + threadIdx.x;
    if (i < NB * NV * 3) vn[i] = 0.0f;
    if (i < NB * NV) {
        float vx = verts[i * 3 + 0];
        float vy = verts[i * 3 + 1];
        float vz = verts[i * 3 + 2];
        float viewx = -vx;
        float viewy = vy;
        float z = 2.0f - vz;
        float ndcx = (12.0f * viewx) / z;
        float ndcy = (12.0f * viewy) / z;
        vert[i] = make_float4(ndcx, ndcy, z, 0.0f);
    }
}

__global__ __launch_bounds__(256) void k_face(const float* __restrict__ verts,
                                              const int* __restrict__ faces,
                                              const float4* __restrict__ vert,
                                              float* __restrict__ vn,
                                              float4* __restrict__ face) {
    int i = blockIdx.x * 256 + threadIdx.x;
    if (i >= NB * NF) return;
    int b = i / NF;
    int f = i - b * NF;
    int i0 = faces[f * 3 + 0];
    int i1 = faces[f * 3 + 1];
    int i2 = faces[f * 3 + 2];
    float4 p0 = vert[b * NV + i0];
    float4 p1 = vert[b * NV + i1];
    float4 p2 = vert[b * NV + i2];
    float t1 = (p1.x - p0.x) * (p2.y - p0.y);
    float t2 = (p1.y - p0.y) * (p2.x - p0.x);
    float area = t1 - t2;
    float aabs = fabsf(area);
    float area_safe = (aabs < EPSF) ? EPSF : area;
    bool valid = aabs > EPSF;
    float minx, maxx, miny, maxy;
    if (valid) {
        minx = fminf(p0.x, fminf(p1.x, p2.x)) - 1e-3f;
        maxx = fmaxf(p0.x, fmaxf(p1.x, p2.x)) + 1e-3f;
        miny = fminf(p0.y, fminf(p1.y, p2.y)) - 1e-3f;
        maxy = fmaxf(p0.y, fmaxf(p1.y, p2.y)) + 1e-3f;
    } else {
        minx = 1e30f; maxx = -1e30f; miny = 1e30f; maxy = -1e30f;
    }
    int o = (b * NF + f) * 4;
    face[o + 0] = make_float4(p2.x - p1.x, p2.y - p1.y, p1.x, p1.y);
    face[o + 1] = make_float4(p0.x - p2.x, p0.y - p2.y, p2.x, p2.y);
    face[o + 2] = make_float4(area_safe, p0.z, p1.z, p2.z);
    face[o + 3] = make_float4(minx, maxx, miny, maxy);

    const float* wv = verts + (size_t)b * NV * 3;
    float ax = wv[i1 * 3 + 0] - wv[i0 * 3 + 0];
    float ay = wv[i1 * 3 + 1] - wv[i0 * 3 + 1];
    float az = wv[i1 * 3 + 2] - wv[i0 * 3 + 2];
    float bx = wv[i2 * 3 + 0] - wv[i0 * 3 + 0];
    float by = wv[i2 * 3 + 1] - wv[i0 * 3 + 1];
    float bz = wv[i2 * 3 + 2] - wv[i0 * 3 + 2];
    float fnx = ay * bz - az * by;
    float fny = az * bx - ax * bz;
    float fnz = ax * by - ay * bx;
    float* vnb = vn + (size_t)b * NV * 3;
    atomicAdd(&vnb[i0 * 3 + 0], fnx);
    atomicAdd(&vnb[i0 * 3 + 1], fny);
    atomicAdd(&vnb[i0 * 3 + 2], fnz);
    atomicAdd(&vnb[i1 * 3 + 0], fnx);
    atomicAdd(&vnb[i1 * 3 + 1], fny);
    atomicAdd(&vnb[i1 * 3 + 2], fnz);
    atomicAdd(&vnb[i2 * 3 + 0], fnx);
    atomicAdd(&vnb[i2 * 3 + 1], fny);
    atomicAdd(&vnb[i2 * 3 + 2], fnz);
}

// Grid: bx = (tile*NB + b)*NCHUNK + chunk — chunk is the FAST dim so a hot
// tile's 16 chunk-blocks land on 16 consecutive CUs (load balance).
// Phase 1: 256 threads ballot-test all chunk faces' bboxes vs the tile rect
// (conservative superset of every lane's bbox test) and order-preserving
// prefix-compact survivors into LDS. Phase 2: lanes scan only relevant faces.
__global__ __launch_bounds__(256) void k_raster(const float4* __restrict__ face,
                                                unsigned long long* __restrict__ dbuf16) {
    __shared__ float4 sface[CHUNK * 4];
    __shared__ int sidx[CHUNK];
    __shared__ int swbase[4];
    __shared__ int scnt;

    int bx = blockIdx.x;
    int chunk = bx & (NCHUNK - 1);
    int tmp = bx >> 4;
    int b = tmp & 1;
    int tile = tmp >> 1; // 0..63
    int f0 = chunk * CHUNK;
    int nf = NF - f0; if (nf > CHUNK) nf = CHUNK;

    int r0 = (tile >> 3) * 16;
    int c0 = (tile & 7) * 16;
    // tile pixel NDC extremes, same formula lanes use (px decreasing in c)
    float txmax = 1.0f - (2.0f * (float)c0 + 1.0f) / 128.0f;
    float txmin = 1.0f - (2.0f * (float)(c0 + 15) + 1.0f) / 128.0f;
    float tymax = 1.0f - (2.0f * (float)r0 + 1.0f) / 128.0f;
    float tymin = 1.0f - (2.0f * (float)(r0 + 15) + 1.0f) / 128.0f;

    const float4* fb = face + (size_t)b * NF * 4;
    int t = threadIdx.x;
    int wid = t >> 6, lid = t & 63;
    bool pass = false;
    float4 bb;
    if (t < nf) {
        bb = fb[(f0 + t) * 4 + 3]; // {minx, maxx, miny, maxy}
        pass = (bb.y >= txmin) && (bb.x <= txmax) && (bb.w >= tymin) && (bb.z <= tymax);
    }
    unsigned long long m = __ballot(pass);
    if (lid == 0) swbase[wid] = __popcll(m);
    __syncthreads();
    if (t == 0) {
        int acc = 0;
        for (int i2 = 0; i2 < 4; ++i2) { int cc = swbase[i2]; swbase[i2] = acc; acc += cc; }
        scnt = acc;
    }
    __syncthreads();
    if (pass) {
        int pos = swbase[wid] + __popcll(m & ((1ull << lid) - 1ull));
        sface[pos * 4 + 0] = fb[(f0 + t) * 4 + 0];
        sface[pos * 4 + 1] = fb[(f0 + t) * 4 + 1];
        sface[pos * 4 + 2] = fb[(f0 + t) * 4 + 2];
        sface[pos * 4 + 3] = bb;
        sidx[pos] = f0 + t;
    }
    __syncthreads();
    int cnt = scnt;

    int r = r0 + ((wid >> 1) * 8) + (lid >> 3);
    int c = c0 + ((wid & 1) * 8) + (lid & 7);
    int p = r * IMG_W + c;
    float px = 1.0f - (2.0f * (float)c + 1.0f) / 128.0f;
    float py = 1.0f - (2.0f * (float)r + 1.0f) / 128.0f;

    unsigned long long best = DINIT;
    for (int j = 0; j < cnt; ++j) {
        float4 fbb = sface[j * 4 + 3];
        if (px >= fbb.x && px <= fbb.y && py >= fbb.z && py <= fbb.w) {
            float4 E0 = sface[j * 4 + 0];
            float4 E1 = sface[j * 4 + 1];
            float4 FD = sface[j * 4 + 2];
            // exact ref order: e = (bx-ax)*(py-ay) - (by-ay)*(px-ax)
            float u1 = E0.x * (py - E0.w);
            float u2 = E0.y * (px - E0.z);
            float e0 = u1 - u2;
            float u3 = E1.x * (py - E1.w);
            float u4 = E1.y * (px - E1.z);
            float e1 = u3 - u4;
            float as = FD.x;
            bool ok = (as > 0.0f) ? (e0 >= 0.0f && e1 >= 0.0f)
                                  : (e0 <= 0.0f && e1 <= 0.0f);
            if (ok) {
                float b0 = e0 / as; // true IEEE division, as in ref
                float b1 = e1 / as;
                float b2 = (1.0f - b0) - b1;
                if (b2 >= 0.0f) {
                    float S = ((b0 / FD.y) + (b1 / FD.z)) + (b2 / FD.w);
                    if (S > EPSF) {
                        float depth = 1.0f / fmaxf(S, EPSF);
                        unsigned long long pk =
                            ((unsigned long long)__float_as_uint(depth) << 32) |
                            (unsigned)sidx[j];
                        if (pk < best) best = pk;
                    }
                }
            }
        }
    }
    dbuf16[((size_t)chunk * NB + b) * HW + p] = best;
}

__global__ __launch_bounds__(256) void k_shade(const float* __restrict__ verts,
                                               const int* __restrict__ faces,
                                               const float4* __restrict__ vert,
                                               const float* __restrict__ vn,
                                               const unsigned long long* __restrict__ dbuf16,
                                               float* __restrict__ out) {
    int i = blockIdx.x * 256 + threadIdx.x; // 0..NB*HW-1
    int b = i >> 14;
    int p = i & (HW - 1);
    unsigned long long pk = DINIT;
    for (int k = 0; k < NCHUNK; ++k) {
        unsigned long long v = dbuf16[((size_t)k * NB + b) * HW + p];
        if (v < pk) pk = v;
    }
    unsigned dbits = (unsigned)(pk >> 32);
    bool hit = dbits < 0x7F800000u;
    float cr = 255.0f, cg = 255.0f, cb = 255.0f, alpha = 0.0f;
    if (hit) {
        alpha = 1.0f;
        int f = (int)(unsigned)(pk & 0xFFFFFFFFull);
        int row = p >> 7;
        int col = p & 127;
        float px = 1.0f - (2.0f * (float)col + 1.0f) / 128.0f;
        float py = 1.0f - (2.0f * (float)row + 1.0f) / 128.0f;
        int i0 = faces[f * 3 + 0];
        int i1 = faces[f * 3 + 1];
        int i2 = faces[f * 3 + 2];
        float4 a0 = vert[b * NV + i0];
        float4 a1 = vert[b * NV + i1];
        float4 a2 = vert[b * NV + i2];
        float t1 = (a1.x - a0.x) * (a2.y - a0.y);
        float t2 = (a1.y - a0.y) * (a2.x - a0.x);
        float ar = t1 - t2;
        ar = (fabsf(ar) < EPSF) ? EPSF : ar;
        float u1 = (a2.x - a1.x) * (py - a1.y);
        float u2 = (a2.y - a1.y) * (px - a1.x);
        float bb0 = (u1 - u2) / ar;
        float u3 = (a0.x - a2.x) * (py - a2.y);
        float u4 = (a0.y - a2.y) * (px - a2.x);
        float bb1 = (u3 - u4) / ar;
        float bb2 = (1.0f - bb0) - bb1;
        float w0 = bb0 / a0.z;
        float w1 = bb1 / a1.z;
        float w2 = bb2 / a2.z;
        float denom = ((w0 + w1) + w2) + EPSF;
        float pc0 = w0 / denom;
        float pc1 = w1 / denom;
        float pc2 = w2 / denom;

        const float* wv = verts + (size_t)b * NV * 3;
        float v0x = wv[i0 * 3 + 0], v0y = wv[i0 * 3 + 1], v0z = wv[i0 * 3 + 2];
        float v1x = wv[i1 * 3 + 0], v1y = wv[i1 * 3 + 1], v1z = wv[i1 * 3 + 2];
        float v2x = wv[i2 * 3 + 0], v2y = wv[i2 * 3 + 1], v2z = wv[i2 * 3 + 2];
        float posx = (pc0 * v0x + pc1 * v1x) + pc2 * v2x;
        float posy = (pc0 * v0y + pc1 * v1y) + pc2 * v2y;
        float posz = (pc0 * v0z + pc1 * v1z) + pc2 * v2z;

        const float* vnb = vn + (size_t)b * NV * 3;
        float n0x = vnb[i0 * 3 + 0], n0y = vnb[i0 * 3 + 1], n0z = vnb[i0 * 3 + 2];
        float n1x = vnb[i1 * 3 + 0], n1y = vnb[i1 * 3 + 1], n1z = vnb[i1 * 3 + 2];
        float n2x = vnb[i2 * 3 + 0], n2y = vnb[i2 * 3 + 1], n2z = vnb[i2 * 3 + 2];
        float in0 = 1.0f / (sqrtf(n0x * n0x + n0y * n0y + n0z * n0z) + EPSF);
        float in1 = 1.0f / (sqrtf(n1x * n1x + n1y * n1y + n1z * n1z) + EPSF);
        float in2 = 1.0f / (sqrtf(n2x * n2x + n2y * n2y + n2z * n2z) + EPSF);
        n0x *= in0; n0y *= in0; n0z *= in0;
        n1x *= in1; n1y *= in1; n1z *= in1;
        n2x *= in2; n2y *= in2; n2z *= in2;
        float nx = (pc0 * n0x + pc1 * n1x) + pc2 * n2x;
        float ny = (pc0 * n0y + pc1 * n1y) + pc2 * n2y;
        float nz = (pc0 * n0z + pc1 * n1z) + pc2 * n2z;
        float inn = 1.0f / (sqrtf(nx * nx + ny * ny + nz * nz) + EPSF);
        nx *= inn; ny *= inn; nz *= inn;

        float lx = 0.0f - posx, ly = 1.0f - posy, lz = 3.0f - posz;
        float iln = 1.0f / (sqrtf(lx * lx + ly * ly + lz * lz) + EPSF);
        lx *= iln; ly *= iln; lz *= iln;
        float vx = 0.0f - posx, vy = 0.0f - posy, vz = 2.0f - posz;
        float ivn = 1.0f / (sqrtf(vx * vx + vy * vy + vz * vz) + EPSF);
        vx *= ivn; vy *= ivn; vz *= ivn;

        float ndl = nx * lx + ny * ly + nz * lz;
        float ndlr = fmaxf(ndl, 0.0f);
        float rx = 2.0f * ndl * nx - lx;
        float ry = 2.0f * ndl * ny - ly;
        float rz = 2.0f * ndl * nz - lz;
        float sc = fmaxf(rx * vx + ry * vy + rz * vz, 0.0f);
        float spec = 0.2f * 0.6f * powf(sc, 10.0f);
        float shade = 0.5f * 1.0f + 0.3f * 1.0f * ndlr;
        cr = ((142.0f / 255.0f) * shade + spec) * 255.0f;
        cg = ((179.0f / 255.0f) * shade + spec) * 255.0f;
        cb = ((247.0f / 255.0f) * shade + spec) * 255.0f;
    }
    float* img = out + (size_t)b * 3 * HW;
    img[0 * HW + p] = cr;
    img[1 * HW + p] = cg;
    img[2 * HW + p] = cb;
    out[(size_t)NB * 3 * HW + (size_t)b * HW + p] = alpha;
}

extern "C" void kernel_launch(void* const* d_in, const int* in_sizes, int n_in,
                              void* d_out, int out_size, void* d_ws, size_t ws_size,
                              hipStream_t stream) {
    const float* verts = (const float*)d_in[0]; // [NB, NV, 3]
    const int* faces = (const int*)d_in[1];     // [NF, 3]
    char* ws = (char*)d_ws;
    float4* vert = (float4*)(ws + 0);
    float* vn = (float*)(ws + OFF_VN);
    float4* face = (float4*)(ws + OFF_FACE);
    unsigned long long* dbuf16 = (unsigned long long*)(ws + OFF_DBUF);
    float* out = (float*)d_out;

    k_init<<<(NB * NV * 3 + 255) / 256, 256, 0, stream>>>(verts, vert, vn);
    k_face<<<(NB * NF + 255) / 256, 256, 0, stream>>>(verts, faces, vert, vn, face);
    k_raster<<<64 * NB * NCHUNK, 256, 0, stream>>>(face, dbuf16);
    k_shade<<<(NB * HW) / 256, 256, 0, stream>>>(verts, faces, vert, vn, dbuf16, out);
}

// Round 5
// 111.258 us; speedup vs baseline: 1.5752x; 1.1518x over previous
//
#include <hip/hip_runtime.h>
#include <math.h>

// Exact IEEE semantics in the visibility path: no fma contraction anywhere.
#pragma clang fp contract(off)

#define IMG_H 128
#define IMG_W 128
#define HW (IMG_H * IMG_W)
#define NB 2
#define NV 1300
#define NF 2500
#define EPSF 1e-8f
#define NCHUNK 32
#define CHUNK ((NF + NCHUNK - 1) / NCHUNK) // 79
#define NBLK (64 * NB * NCHUNK)            // 4096

// ws layout (bytes):
//   vert   f4 [NB*NV]            @ 0       (41600 B)  {ndcx, ndcy, z, 0}
//   vn     f32[NB*NV*3]          @ 41600   (31200 B)
//   face   f4 [NB*NF*4]          @ 72800   (320000 B)
//   dbuf   u64[NCHUNK][NB][HW]   @ 392800  (8 MB)     per-chunk depth|idx
#define OFF_VN 41600
#define OFF_FACE 72800
#define OFF_DBUF 392800

#define DINIT 0x7F800000FFFFFFFFull // depth=+inf, fidx=~0

__global__ __launch_bounds__(256) void k_init(const float* __restrict__ verts,
                                              float4* __restrict__ vert,
                                              float* __restrict__ vn) {
    int i = blockIdx.x * 256 + threadIdx.x;
    if (i < NB * NV * 3) vn[i] = 0.0f;
    if (i < NB * NV) {
        float vx = verts[i * 3 + 0];
        float vy = verts[i * 3 + 1];
        float vz = verts[i * 3 + 2];
        float viewx = -vx;
        float viewy = vy;
        float z = 2.0f - vz;
        float ndcx = (12.0f * viewx) / z;
        float ndcy = (12.0f * viewy) / z;
        vert[i] = make_float4(ndcx, ndcy, z, 0.0f);
    }
}

__global__ __launch_bounds__(256) void k_face(const float* __restrict__ verts,
                                              const int* __restrict__ faces,
                                              const float4* __restrict__ vert,
                                              float* __restrict__ vn,
                                              float4* __restrict__ face) {
    int i = blockIdx.x * 256 + threadIdx.x;
    if (i >= NB * NF) return;
    int b = i / NF;
    int f = i - b * NF;
    int i0 = faces[f * 3 + 0];
    int i1 = faces[f * 3 + 1];
    int i2 = faces[f * 3 + 2];
    float4 p0 = vert[b * NV + i0];
    float4 p1 = vert[b * NV + i1];
    float4 p2 = vert[b * NV + i2];
    float t1 = (p1.x - p0.x) * (p2.y - p0.y);
    float t2 = (p1.y - p0.y) * (p2.x - p0.x);
    float area = t1 - t2;
    float aabs = fabsf(area);
    float area_safe = (aabs < EPSF) ? EPSF : area;
    bool valid = aabs > EPSF;
    float minx, maxx, miny, maxy;
    if (valid) {
        minx = fminf(p0.x, fminf(p1.x, p2.x)) - 1e-3f;
        maxx = fmaxf(p0.x, fmaxf(p1.x, p2.x)) + 1e-3f;
        miny = fminf(p0.y, fminf(p1.y, p2.y)) - 1e-3f;
        maxy = fmaxf(p0.y, fmaxf(p1.y, p2.y)) + 1e-3f;
    } else {
        minx = 1e30f; maxx = -1e30f; miny = 1e30f; maxy = -1e30f;
    }
    int o = (b * NF + f) * 4;
    face[o + 0] = make_float4(p2.x - p1.x, p2.y - p1.y, p1.x, p1.y);
    face[o + 1] = make_float4(p0.x - p2.x, p0.y - p2.y, p2.x, p2.y);
    face[o + 2] = make_float4(area_safe, p0.z, p1.z, p2.z);
    face[o + 3] = make_float4(minx, maxx, miny, maxy);

    const float* wv = verts + (size_t)b * NV * 3;
    float ax = wv[i1 * 3 + 0] - wv[i0 * 3 + 0];
    float ay = wv[i1 * 3 + 1] - wv[i0 * 3 + 1];
    float az = wv[i1 * 3 + 2] - wv[i0 * 3 + 2];
    float bx = wv[i2 * 3 + 0] - wv[i0 * 3 + 0];
    float by = wv[i2 * 3 + 1] - wv[i0 * 3 + 1];
    float bz = wv[i2 * 3 + 2] - wv[i0 * 3 + 2];
    float fnx = ay * bz - az * by;
    float fny = az * bx - ax * bz;
    float fnz = ax * by - ay * bx;
    float* vnb = vn + (size_t)b * NV * 3;
    atomicAdd(&vnb[i0 * 3 + 0], fnx);
    atomicAdd(&vnb[i0 * 3 + 1], fny);
    atomicAdd(&vnb[i0 * 3 + 2], fnz);
    atomicAdd(&vnb[i1 * 3 + 0], fnx);
    atomicAdd(&vnb[i1 * 3 + 1], fny);
    atomicAdd(&vnb[i1 * 3 + 2], fnz);
    atomicAdd(&vnb[i2 * 3 + 0], fnx);
    atomicAdd(&vnb[i2 * 3 + 1], fny);
    atomicAdd(&vnb[i2 * 3 + 2], fnz);
}

// blockIdx is scrambled by an odd-multiplier bijection mod 4096 so that the
// hot central tiles (geometry is centered at NDC 0) scatter across all CUs
// instead of serializing on a 32-CU column band (R4's tail: tile*32 mod 256
// is constant per image column). Phase 1: ballot-compact the chunk's faces
// vs the tile rect into LDS (order-preserving). Phase 2: 8x8-px waves scan.
__global__ __launch_bounds__(256) void k_raster(const float4* __restrict__ face,
                                                unsigned long long* __restrict__ dbuf) {
    __shared__ float4 sface[CHUNK * 4];
    __shared__ int sidx[CHUNK];
    __shared__ int swbase[4];
    __shared__ int scnt;

    int idx = (blockIdx.x * 1213) & (NBLK - 1); // odd mult -> bijection
    int chunk = idx & (NCHUNK - 1);
    int tmp = idx >> 5;
    int b = tmp & 1;
    int tile = tmp >> 1; // 0..63
    int f0 = chunk * CHUNK;
    int nf = NF - f0; if (nf > CHUNK) nf = CHUNK;

    int r0 = (tile >> 3) * 16;
    int c0 = (tile & 7) * 16;
    float txmax = 1.0f - (2.0f * (float)c0 + 1.0f) / 128.0f;
    float txmin = 1.0f - (2.0f * (float)(c0 + 15) + 1.0f) / 128.0f;
    float tymax = 1.0f - (2.0f * (float)r0 + 1.0f) / 128.0f;
    float tymin = 1.0f - (2.0f * (float)(r0 + 15) + 1.0f) / 128.0f;

    const float4* fb = face + (size_t)b * NF * 4;
    int t = threadIdx.x;
    int wid = t >> 6, lid = t & 63;
    bool pass = false;
    float4 bb;
    if (t < nf) {
        bb = fb[(f0 + t) * 4 + 3]; // {minx, maxx, miny, maxy}
        pass = (bb.y >= txmin) && (bb.x <= txmax) && (bb.w >= tymin) && (bb.z <= tymax);
    }
    unsigned long long m = __ballot(pass);
    if (lid == 0) swbase[wid] = __popcll(m);
    __syncthreads();
    if (t == 0) {
        int acc = 0;
        for (int i2 = 0; i2 < 4; ++i2) { int cc = swbase[i2]; swbase[i2] = acc; acc += cc; }
        scnt = acc;
    }
    __syncthreads();
    if (pass) {
        int pos = swbase[wid] + __popcll(m & ((1ull << lid) - 1ull));
        sface[pos * 4 + 0] = fb[(f0 + t) * 4 + 0];
        sface[pos * 4 + 1] = fb[(f0 + t) * 4 + 1];
        sface[pos * 4 + 2] = fb[(f0 + t) * 4 + 2];
        sface[pos * 4 + 3] = bb;
        sidx[pos] = f0 + t;
    }
    __syncthreads();
    int cnt = scnt;

    int r = r0 + ((wid >> 1) * 8) + (lid >> 3);
    int c = c0 + ((wid & 1) * 8) + (lid & 7);
    int p = r * IMG_W + c;
    float px = 1.0f - (2.0f * (float)c + 1.0f) / 128.0f;
    float py = 1.0f - (2.0f * (float)r + 1.0f) / 128.0f;

    unsigned long long best = DINIT;
    for (int j = 0; j < cnt; ++j) {
        float4 fbb = sface[j * 4 + 3];
        if (px >= fbb.x && px <= fbb.y && py >= fbb.z && py <= fbb.w) {
            float4 E0 = sface[j * 4 + 0];
            float4 E1 = sface[j * 4 + 1];
            float4 FD = sface[j * 4 + 2];
            // exact ref order: e = (bx-ax)*(py-ay) - (by-ay)*(px-ax)
            float u1 = E0.x * (py - E0.w);
            float u2 = E0.y * (px - E0.z);
            float e0 = u1 - u2;
            float u3 = E1.x * (py - E1.w);
            float u4 = E1.y * (px - E1.z);
            float e1 = u3 - u4;
            float as = FD.x;
            bool ok = (as > 0.0f) ? (e0 >= 0.0f && e1 >= 0.0f)
                                  : (e0 <= 0.0f && e1 <= 0.0f);
            if (ok) {
                float b0 = e0 / as; // true IEEE division, as in ref
                float b1 = e1 / as;
                float b2 = (1.0f - b0) - b1;
                if (b2 >= 0.0f) {
                    float S = ((b0 / FD.y) + (b1 / FD.z)) + (b2 / FD.w);
                    if (S > EPSF) {
                        float depth = 1.0f / fmaxf(S, EPSF);
                        unsigned long long pk =
                            ((unsigned long long)__float_as_uint(depth) << 32) |
                            (unsigned)sidx[j];
                        if (pk < best) best = pk;
                    }
                }
            }
        }
    }
    dbuf[((size_t)chunk * NB + b) * HW + p] = best;
}

__global__ __launch_bounds__(256) void k_shade(const float* __restrict__ verts,
                                               const int* __restrict__ faces,
                                               const float4* __restrict__ vert,
                                               const float* __restrict__ vn,
                                               const unsigned long long* __restrict__ dbuf,
                                               float* __restrict__ out) {
    int i = blockIdx.x * 256 + threadIdx.x; // 0..NB*HW-1
    int b = i >> 14;
    int p = i & (HW - 1);
    unsigned long long pk = DINIT;
    for (int k = 0; k < NCHUNK; ++k) {
        unsigned long long v = dbuf[((size_t)k * NB + b) * HW + p];
        if (v < pk) pk = v;
    }
    unsigned dbits = (unsigned)(pk >> 32);
    bool hit = dbits < 0x7F800000u;
    float cr = 255.0f, cg = 255.0f, cb = 255.0f, alpha = 0.0f;
    if (hit) {
        alpha = 1.0f;
        int f = (int)(unsigned)(pk & 0xFFFFFFFFull);
        int row = p >> 7;
        int col = p & 127;
        float px = 1.0f - (2.0f * (float)col + 1.0f) / 128.0f;
        float py = 1.0f - (2.0f * (float)row + 1.0f) / 128.0f;
        int i0 = faces[f * 3 + 0];
        int i1 = faces[f * 3 + 1];
        int i2 = faces[f * 3 + 2];
        float4 a0 = vert[b * NV + i0];
        float4 a1 = vert[b * NV + i1];
        float4 a2 = vert[b * NV + i2];
        float t1 = (a1.x - a0.x) * (a2.y - a0.y);
        float t2 = (a1.y - a0.y) * (a2.x - a0.x);
        float ar = t1 - t2;
        ar = (fabsf(ar) < EPSF) ? EPSF : ar;
        float u1 = (a2.x - a1.x) * (py - a1.y);
        float u2 = (a2.y - a1.y) * (px - a1.x);
        float bb0 = (u1 - u2) / ar;
        float u3 = (a0.x - a2.x) * (py - a2.y);
        float u4 = (a0.y - a2.y) * (px - a2.x);
        float bb1 = (u3 - u4) / ar;
        float bb2 = (1.0f - bb0) - bb1;
        float w0 = bb0 / a0.z;
        float w1 = bb1 / a1.z;
        float w2 = bb2 / a2.z;
        float denom = ((w0 + w1) + w2) + EPSF;
        float pc0 = w0 / denom;
        float pc1 = w1 / denom;
        float pc2 = w2 / denom;

        const float* wv = verts + (size_t)b * NV * 3;
        float v0x = wv[i0 * 3 + 0], v0y = wv[i0 * 3 + 1], v0z = wv[i0 * 3 + 2];
        float v1x = wv[i1 * 3 + 0], v1y = wv[i1 * 3 + 1], v1z = wv[i1 * 3 + 2];
        float v2x = wv[i2 * 3 + 0], v2y = wv[i2 * 3 + 1], v2z = wv[i2 * 3 + 2];
        float posx = (pc0 * v0x + pc1 * v1x) + pc2 * v2x;
        float posy = (pc0 * v0y + pc1 * v1y) + pc2 * v2y;
        float posz = (pc0 * v0z + pc1 * v1z) + pc2 * v2z;

        const float* vnb = vn + (size_t)b * NV * 3;
        float n0x = vnb[i0 * 3 + 0], n0y = vnb[i0 * 3 + 1], n0z = vnb[i0 * 3 + 2];
        float n1x = vnb[i1 * 3 + 0], n1y = vnb[i1 * 3 + 1], n1z = vnb[i1 * 3 + 2];
        float n2x = vnb[i2 * 3 + 0], n2y = vnb[i2 * 3 + 1], n2z = vnb[i2 * 3 + 2];
        float in0 = 1.0f / (sqrtf(n0x * n0x + n0y * n0y + n0z * n0z) + EPSF);
        float in1 = 1.0f / (sqrtf(n1x * n1x + n1y * n1y + n1z * n1z) + EPSF);
        float in2 = 1.0f / (sqrtf(n2x * n2x + n2y * n2y + n2z * n2z) + EPSF);
        n0x *= in0; n0y *= in0; n0z *= in0;
        n1x *= in1; n1y *= in1; n1z *= in1;
        n2x *= in2; n2y *= in2; n2z *= in2;
        float nx = (pc0 * n0x + pc1 * n1x) + pc2 * n2x;
        float ny = (pc0 * n0y + pc1 * n1y) + pc2 * n2y;
        float nz = (pc0 * n0z + pc1 * n1z) + pc2 * n2z;
        float inn = 1.0f / (sqrtf(nx * nx + ny * ny + nz * nz) + EPSF);
        nx *= inn; ny *= inn; nz *= inn;

        float lx = 0.0f - posx, ly = 1.0f - posy, lz = 3.0f - posz;
        float iln = 1.0f / (sqrtf(lx * lx + ly * ly + lz * lz) + EPSF);
        lx *= iln; ly *= iln; lz *= iln;
        float vx = 0.0f - posx, vy = 0.0f - posy, vz = 2.0f - posz;
        float ivn = 1.0f / (sqrtf(vx * vx + vy * vy + vz * vz) + EPSF);
        vx *= ivn; vy *= ivn; vz *= ivn;

        float ndl = nx * lx + ny * ly + nz * lz;
        float ndlr = fmaxf(ndl, 0.0f);
        float rx = 2.0f * ndl * nx - lx;
        float ry = 2.0f * ndl * ny - ly;
        float rz = 2.0f * ndl * nz - lz;
        float sc = fmaxf(rx * vx + ry * vy + rz * vz, 0.0f);
        float spec = 0.2f * 0.6f * powf(sc, 10.0f);
        float shade = 0.5f * 1.0f + 0.3f * 1.0f * ndlr;
        cr = ((142.0f / 255.0f) * shade + spec) * 255.0f;
        cg = ((179.0f / 255.0f) * shade + spec) * 255.0f;
        cb = ((247.0f / 255.0f) * shade + spec) * 255.0f;
    }
    float* img = out + (size_t)b * 3 * HW;
    img[0 * HW + p] = cr;
    img[1 * HW + p] = cg;
    img[2 * HW + p] = cb;
    out[(size_t)NB * 3 * HW + (size_t)b * HW + p] = alpha;
}

extern "C" void kernel_launch(void* const* d_in, const int* in_sizes, int n_in,
                              void* d_out, int out_size, void* d_ws, size_t ws_size,
                              hipStream_t stream) {
    const float* verts = (const float*)d_in[0]; // [NB, NV, 3]
    const int* faces = (const int*)d_in[1];     // [NF, 3]
    char* ws = (char*)d_ws;
    float4* vert = (float4*)(ws + 0);
    float* vn = (float*)(ws + OFF_VN);
    float4* face = (float4*)(ws + OFF_FACE);
    unsigned long long* dbuf = (unsigned long long*)(ws + OFF_DBUF);
    float* out = (float*)d_out;

    k_init<<<(NB * NV * 3 + 255) / 256, 256, 0, stream>>>(verts, vert, vn);
    k_face<<<(NB * NF + 255) / 256, 256, 0, stream>>>(verts, faces, vert, vn, face);
    k_raster<<<NBLK, 256, 0, stream>>>(face, dbuf);
    k_shade<<<(NB * HW) / 256, 256, 0, stream>>>(verts, faces, vert, vn, dbuf, out);
}

// Round 6
// 103.501 us; speedup vs baseline: 1.6933x; 1.0749x over previous
//
#include <hip/hip_runtime.h>
#include <math.h>

// Exact IEEE semantics in the visibility path: no fma contraction anywhere.
#pragma clang fp contract(off)

#define IMG_H 128
#define IMG_W 128
#define HW (IMG_H * IMG_W)
#define NB 2
#define NV 1300
#define NF 2500
#define EPSF 1e-8f
#define NCHUNK 32
#define CHUNK ((NF + NCHUNK - 1) / NCHUNK) // 79
#define NREG 128                            // 8x16 grid of 16w x 8h px regions
#define NBLK (NREG * NB * NCHUNK)           // 8192

// ws layout (bytes):
//   vn     f32[NB*NV*3]          @ 0       (31200 B)
//   face   f4 [NB*NF*4]          @ 31232   (320000 B)
//   dbuf   u64[NCHUNK][NB][HW]   @ 351488  (8 MB)     per-chunk depth|idx
#define OFF_FACE 31232
#define OFF_DBUF 351488

#define DINIT 0x7F800000FFFFFFFFull // depth=+inf, fidx=~0

__global__ __launch_bounds__(256) void k_face(const float* __restrict__ verts,
                                              const int* __restrict__ faces,
                                              float* __restrict__ vn,
                                              float4* __restrict__ face) {
    int i = blockIdx.x * 256 + threadIdx.x;
    if (i >= NB * NF) return;
    int b = i / NF;
    int f = i - b * NF;
    int i0 = faces[f * 3 + 0];
    int i1 = faces[f * 3 + 1];
    int i2 = faces[f * 3 + 2];
    const float* wv = verts + (size_t)b * NV * 3;
    // transform, bit-identical to ref: ndc = (12*(-vx))/(2-vz), z = 2-vz
    float v0x = wv[i0 * 3 + 0], v0y = wv[i0 * 3 + 1], v0z = wv[i0 * 3 + 2];
    float v1x = wv[i1 * 3 + 0], v1y = wv[i1 * 3 + 1], v1z = wv[i1 * 3 + 2];
    float v2x = wv[i2 * 3 + 0], v2y = wv[i2 * 3 + 1], v2z = wv[i2 * 3 + 2];
    float z0 = 2.0f - v0z, z1 = 2.0f - v1z, z2 = 2.0f - v2z;
    float p0x = (12.0f * (-v0x)) / z0, p0y = (12.0f * v0y) / z0;
    float p1x = (12.0f * (-v1x)) / z1, p1y = (12.0f * v1y) / z1;
    float p2x = (12.0f * (-v2x)) / z2, p2y = (12.0f * v2y) / z2;

    float t1 = (p1x - p0x) * (p2y - p0y);
    float t2 = (p1y - p0y) * (p2x - p0x);
    float area = t1 - t2;
    float aabs = fabsf(area);
    float area_safe = (aabs < EPSF) ? EPSF : area;
    bool valid = aabs > EPSF;
    float minx, maxx, miny, maxy;
    if (valid) {
        minx = fminf(p0x, fminf(p1x, p2x)) - 1e-3f;
        maxx = fmaxf(p0x, fmaxf(p1x, p2x)) + 1e-3f;
        miny = fminf(p0y, fminf(p1y, p2y)) - 1e-3f;
        maxy = fmaxf(p0y, fmaxf(p1y, p2y)) + 1e-3f;
    } else {
        minx = 1e30f; maxx = -1e30f; miny = 1e30f; maxy = -1e30f;
    }
    int o = (b * NF + f) * 4;
    face[o + 0] = make_float4(p2x - p1x, p2y - p1y, p1x, p1y);
    face[o + 1] = make_float4(p0x - p2x, p0y - p2y, p2x, p2y);
    face[o + 2] = make_float4(area_safe, z0, z1, z2);
    face[o + 3] = make_float4(minx, maxx, miny, maxy);

    // world-space face normal -> scatter to vertex normals
    float ax = v1x - v0x, ay = v1y - v0y, az = v1z - v0z;
    float bx = v2x - v0x, by = v2y - v0y, bz = v2z - v0z;
    float fnx = ay * bz - az * by;
    float fny = az * bx - ax * bz;
    float fnz = ax * by - ay * bx;
    float* vnb = vn + (size_t)b * NV * 3;
    atomicAdd(&vnb[i0 * 3 + 0], fnx);
    atomicAdd(&vnb[i0 * 3 + 1], fny);
    atomicAdd(&vnb[i0 * 3 + 2], fnz);
    atomicAdd(&vnb[i1 * 3 + 0], fnx);
    atomicAdd(&vnb[i1 * 3 + 1], fny);
    atomicAdd(&vnb[i1 * 3 + 2], fnz);
    atomicAdd(&vnb[i2 * 3 + 0], fnx);
    atomicAdd(&vnb[i2 * 3 + 1], fny);
    atomicAdd(&vnb[i2 * 3 + 2], fnz);
}

// Block = 128 threads = 2 waves, covering a 16w x 8h px region (each wave an
// 8x8 quadrant). bx = (region*NB+b)*NCHUNK+chunk: same-CU blocks (bx mod 256)
// land on regions spaced 4 apart -> all row-bands x balanced column pairs.
// Phase 1: threads 0..CHUNK-1 ballot-test the chunk's face bboxes vs the
// region rect, order-preserving compact into LDS. Phase 2: waves scan.
__global__ __launch_bounds__(128) void k_raster(const float4* __restrict__ face,
                                                unsigned long long* __restrict__ dbuf) {
    __shared__ float4 sface[CHUNK * 4];
    __shared__ int sidx[CHUNK];
    __shared__ int swbase[2];
    __shared__ int scnt;

    int bx = blockIdx.x;
    int chunk = bx & (NCHUNK - 1);
    int tmp = bx >> 5;
    int b = tmp & 1;
    int reg = tmp >> 1;       // 0..127
    int r0 = (reg >> 3) * 8;  // 16 row-bands of 8 px
    int c0 = (reg & 7) * 16;  // 8 col-bands of 16 px
    int f0 = chunk * CHUNK;
    int nf = NF - f0; if (nf > CHUNK) nf = CHUNK;

    float txmax = 1.0f - (2.0f * (float)c0 + 1.0f) / 128.0f;
    float txmin = 1.0f - (2.0f * (float)(c0 + 15) + 1.0f) / 128.0f;
    float tymax = 1.0f - (2.0f * (float)r0 + 1.0f) / 128.0f;
    float tymin = 1.0f - (2.0f * (float)(r0 + 7) + 1.0f) / 128.0f;

    const float4* fb = face + (size_t)b * NF * 4;
    int t = threadIdx.x;
    int wid = t >> 6, lid = t & 63;
    bool pass = false;
    float4 bb;
    if (t < nf) {
        bb = fb[(f0 + t) * 4 + 3]; // {minx, maxx, miny, maxy}
        pass = (bb.y >= txmin) && (bb.x <= txmax) && (bb.w >= tymin) && (bb.z <= tymax);
    }
    unsigned long long m = __ballot(pass);
    if (lid == 0) swbase[wid] = __popcll(m);
    __syncthreads();
    int base0 = swbase[0];
    if (pass) {
        int pos = (wid ? base0 : 0) + __popcll(m & ((1ull << lid) - 1ull));
        sface[pos * 4 + 0] = fb[(f0 + t) * 4 + 0];
        sface[pos * 4 + 1] = fb[(f0 + t) * 4 + 1];
        sface[pos * 4 + 2] = fb[(f0 + t) * 4 + 2];
        sface[pos * 4 + 3] = bb;
        sidx[pos] = f0 + t;
    }
    if (t == 0) scnt = base0 + swbase[1];
    __syncthreads();
    int cnt = scnt;

    int r = r0 + (lid >> 3);
    int c = c0 + wid * 8 + (lid & 7);
    int p = r * IMG_W + c;
    float px = 1.0f - (2.0f * (float)c + 1.0f) / 128.0f;
    float py = 1.0f - (2.0f * (float)r + 1.0f) / 128.0f;

    unsigned long long best = DINIT;
    for (int j = 0; j < cnt; ++j) {
        float4 fbb = sface[j * 4 + 3];
        if (px >= fbb.x && px <= fbb.y && py >= fbb.z && py <= fbb.w) {
            float4 E0 = sface[j * 4 + 0];
            float4 E1 = sface[j * 4 + 1];
            float4 FD = sface[j * 4 + 2];
            // exact ref order: e = (bx-ax)*(py-ay) - (by-ay)*(px-ax)
            float u1 = E0.x * (py - E0.w);
            float u2 = E0.y * (px - E0.z);
            float e0 = u1 - u2;
            float u3 = E1.x * (py - E1.w);
            float u4 = E1.y * (px - E1.z);
            float e1 = u3 - u4;
            float as = FD.x;
            bool ok = (as > 0.0f) ? (e0 >= 0.0f && e1 >= 0.0f)
                                  : (e0 <= 0.0f && e1 <= 0.0f);
            if (ok) {
                float b0 = e0 / as; // true IEEE division, as in ref
                float b1 = e1 / as;
                float b2 = (1.0f - b0) - b1;
                if (b2 >= 0.0f) {
                    float S = ((b0 / FD.y) + (b1 / FD.z)) + (b2 / FD.w);
                    if (S > EPSF) {
                        float depth = 1.0f / fmaxf(S, EPSF);
                        unsigned long long pk =
                            ((unsigned long long)__float_as_uint(depth) << 32) |
                            (unsigned)sidx[j];
                        if (pk < best) best = pk;
                    }
                }
            }
        }
    }
    dbuf[((size_t)chunk * NB + b) * HW + p] = best;
}

__global__ __launch_bounds__(256) void k_shade(const float* __restrict__ verts,
                                               const int* __restrict__ faces,
                                               const float* __restrict__ vn,
                                               const unsigned long long* __restrict__ dbuf,
                                               float* __restrict__ out) {
    int i = blockIdx.x * 256 + threadIdx.x; // 0..NB*HW-1
    int b = i >> 14;
    int p = i & (HW - 1);
    unsigned long long pk = DINIT;
    for (int k = 0; k < NCHUNK; ++k) {
        unsigned long long v = dbuf[((size_t)k * NB + b) * HW + p];
        if (v < pk) pk = v;
    }
    unsigned dbits = (unsigned)(pk >> 32);
    bool hit = dbits < 0x7F800000u;
    float cr = 255.0f, cg = 255.0f, cb = 255.0f, alpha = 0.0f;
    if (hit) {
        alpha = 1.0f;
        int f = (int)(unsigned)(pk & 0xFFFFFFFFull);
        int row = p >> 7;
        int col = p & 127;
        float px = 1.0f - (2.0f * (float)col + 1.0f) / 128.0f;
        float py = 1.0f - (2.0f * (float)row + 1.0f) / 128.0f;
        int i0 = faces[f * 3 + 0];
        int i1 = faces[f * 3 + 1];
        int i2 = faces[f * 3 + 2];
        const float* wv = verts + (size_t)b * NV * 3;
        float v0x = wv[i0 * 3 + 0], v0y = wv[i0 * 3 + 1], v0z = wv[i0 * 3 + 2];
        float v1x = wv[i1 * 3 + 0], v1y = wv[i1 * 3 + 1], v1z = wv[i1 * 3 + 2];
        float v2x = wv[i2 * 3 + 0], v2y = wv[i2 * 3 + 1], v2z = wv[i2 * 3 + 2];
        // transform, bit-identical to k_face/ref
        float z0 = 2.0f - v0z, z1 = 2.0f - v1z, z2 = 2.0f - v2z;
        float a0x = (12.0f * (-v0x)) / z0, a0y = (12.0f * v0y) / z0;
        float a1x = (12.0f * (-v1x)) / z1, a1y = (12.0f * v1y) / z1;
        float a2x = (12.0f * (-v2x)) / z2, a2y = (12.0f * v2y) / z2;

        float t1 = (a1x - a0x) * (a2y - a0y);
        float t2 = (a1y - a0y) * (a2x - a0x);
        float ar = t1 - t2;
        ar = (fabsf(ar) < EPSF) ? EPSF : ar;
        float u1 = (a2x - a1x) * (py - a1y);
        float u2 = (a2y - a1y) * (px - a1x);
        float bb0 = (u1 - u2) / ar;
        float u3 = (a0x - a2x) * (py - a2y);
        float u4 = (a0y - a2y) * (px - a2x);
        float bb1 = (u3 - u4) / ar;
        float bb2 = (1.0f - bb0) - bb1;
        float w0 = bb0 / z0;
        float w1 = bb1 / z1;
        float w2 = bb2 / z2;
        float denom = ((w0 + w1) + w2) + EPSF;
        float pc0 = w0 / denom;
        float pc1 = w1 / denom;
        float pc2 = w2 / denom;

        float posx = (pc0 * v0x + pc1 * v1x) + pc2 * v2x;
        float posy = (pc0 * v0y + pc1 * v1y) + pc2 * v2y;
        float posz = (pc0 * v0z + pc1 * v1z) + pc2 * v2z;

        const float* vnb = vn + (size_t)b * NV * 3;
        float n0x = vnb[i0 * 3 + 0], n0y = vnb[i0 * 3 + 1], n0z = vnb[i0 * 3 + 2];
        float n1x = vnb[i1 * 3 + 0], n1y = vnb[i1 * 3 + 1], n1z = vnb[i1 * 3 + 2];
        float n2x = vnb[i2 * 3 + 0], n2y = vnb[i2 * 3 + 1], n2z = vnb[i2 * 3 + 2];
        float in0 = 1.0f / (sqrtf(n0x * n0x + n0y * n0y + n0z * n0z) + EPSF);
        float in1 = 1.0f / (sqrtf(n1x * n1x + n1y * n1y + n1z * n1z) + EPSF);
        float in2 = 1.0f / (sqrtf(n2x * n2x + n2y * n2y + n2z * n2z) + EPSF);
        n0x *= in0; n0y *= in0; n0z *= in0;
        n1x *= in1; n1y *= in1; n1z *= in1;
        n2x *= in2; n2y *= in2; n2z *= in2;
        float nx = (pc0 * n0x + pc1 * n1x) + pc2 * n2x;
        float ny = (pc0 * n0y + pc1 * n1y) + pc2 * n2y;
        float nz = (pc0 * n0z + pc1 * n1z) + pc2 * n2z;
        float inn = 1.0f / (sqrtf(nx * nx + ny * ny + nz * nz) + EPSF);
        nx *= inn; ny *= inn; nz *= inn;

        float lx = 0.0f - posx, ly = 1.0f - posy, lz = 3.0f - posz;
        float iln = 1.0f / (sqrtf(lx * lx + ly * ly + lz * lz) + EPSF);
        lx *= iln; ly *= iln; lz *= iln;
        float vx = 0.0f - posx, vy = 0.0f - posy, vz = 2.0f - posz;
        float ivn = 1.0f / (sqrtf(vx * vx + vy * vy + vz * vz) + EPSF);
        vx *= ivn; vy *= ivn; vz *= ivn;

        float ndl = nx * lx + ny * ly + nz * lz;
        float ndlr = fmaxf(ndl, 0.0f);
        float rx = 2.0f * ndl * nx - lx;
        float ry = 2.0f * ndl * ny - ly;
        float rz = 2.0f * ndl * nz - lz;
        float sc = fmaxf(rx * vx + ry * vy + rz * vz, 0.0f);
        float spec = 0.2f * 0.6f * powf(sc, 10.0f);
        float shade = 0.5f * 1.0f + 0.3f * 1.0f * ndlr;
        cr = ((142.0f / 255.0f) * shade + spec) * 255.0f;
        cg = ((179.0f / 255.0f) * shade + spec) * 255.0f;
        cb = ((247.0f / 255.0f) * shade + spec) * 255.0f;
    }
    float* img = out + (size_t)b * 3 * HW;
    img[0 * HW + p] = cr;
    img[1 * HW + p] = cg;
    img[2 * HW + p] = cb;
    out[(size_t)NB * 3 * HW + (size_t)b * HW + p] = alpha;
}

extern "C" void kernel_launch(void* const* d_in, const int* in_sizes, int n_in,
                              void* d_out, int out_size, void* d_ws, size_t ws_size,
                              hipStream_t stream) {
    const float* verts = (const float*)d_in[0]; // [NB, NV, 3]
    const int* faces = (const int*)d_in[1];     // [NF, 3]
    char* ws = (char*)d_ws;
    float* vn = (float*)(ws + 0);
    float4* face = (float4*)(ws + OFF_FACE);
    unsigned long long* dbuf = (unsigned long long*)(ws + OFF_DBUF);
    float* out = (float*)d_out;

    hipMemsetAsync(vn, 0, NB * NV * 3 * sizeof(float), stream);
    k_face<<<(NB * NF + 255) / 256, 256, 0, stream>>>(verts, faces, vn, face);
    k_raster<<<NBLK, 128, 0, stream>>>(face, dbuf);
    k_shade<<<(NB * HW) / 256, 256, 0, stream>>>(verts, faces, vn, dbuf, out);
}